// Round 1
// baseline (927.618 us; speedup 1.0000x reference)
//
#include <hip/hip_runtime.h>
#include <hip/hip_bf16.h>

// ---------------------------------------------------------------------------
// SupplyChainGNN: 3-layer GCN (PyG GCNConv semantics) + global mean pool.
//   deg[i]   = 1 + indeg(i)  (self loops added)
//   dinv     = rsqrt(deg)
//   layer:   h = x @ W;  out[i] = sum_{e: dst=i} dinv[src]*dinv[i]*h[src]
//                                + dinv[i]^2 * h[i] + b;  (ReLU on layers 1,2)
// CSR (by dst) is rebuilt on-device every call (workspace is re-poisoned).
// ---------------------------------------------------------------------------

#define F_IN 128

__global__ __launch_bounds__(256) void initdeg_k(int* deg, int M) {
    int i = blockIdx.x * 256 + threadIdx.x;
    if (i < M) deg[i] = 1;  // self loop
}

__global__ __launch_bounds__(256) void count_k(const int* __restrict__ dst, int E,
                                               int* __restrict__ deg) {
    int e = blockIdx.x * 256 + threadIdx.x;
    if (e < E) atomicAdd(&deg[dst[e]], 1);
}

__global__ __launch_bounds__(256) void mkdinv_k(const int* __restrict__ deg,
                                                float* __restrict__ dinv, int M) {
    int i = blockIdx.x * 256 + threadIdx.x;
    if (i < M) dinv[i] = rsqrtf((float)deg[i]);
}

// ---- block-scan of edge counts (deg-1) to build rowptr --------------------
__global__ __launch_bounds__(256) void scan1_k(const int* __restrict__ deg, int M,
                                               int* __restrict__ blksum) {
    __shared__ int sh[256];
    int i = blockIdx.x * 256 + threadIdx.x;
    int v = (i < M) ? deg[i] - 1 : 0;
    sh[threadIdx.x] = v;
    __syncthreads();
    for (int o = 128; o > 0; o >>= 1) {
        if (threadIdx.x < o) sh[threadIdx.x] += sh[threadIdx.x + o];
        __syncthreads();
    }
    if (threadIdx.x == 0) blksum[blockIdx.x] = sh[0];
}

__global__ __launch_bounds__(512) void scan2_k(int* __restrict__ blksum, int nb) {
    // single block, exclusive scan of up to 512 block sums (Hillis-Steele)
    __shared__ int sh[512];
    int tid = threadIdx.x;
    int v = (tid < nb) ? blksum[tid] : 0;
    sh[tid] = v;
    __syncthreads();
    for (int o = 1; o < 512; o <<= 1) {
        int t = (tid >= o) ? sh[tid - o] : 0;
        __syncthreads();
        sh[tid] += t;
        __syncthreads();
    }
    if (tid < nb) blksum[tid] = sh[tid] - v;  // exclusive
}

__global__ __launch_bounds__(256) void scan3_k(const int* __restrict__ deg, int M,
                                               const int* __restrict__ blksum,
                                               int* __restrict__ rowptr,
                                               int* __restrict__ cursor) {
    __shared__ int sh[256];
    int tid = threadIdx.x;
    int i = blockIdx.x * 256 + tid;
    int v = (i < M) ? deg[i] - 1 : 0;
    sh[tid] = v;
    __syncthreads();
    for (int o = 1; o < 256; o <<= 1) {
        int t = (tid >= o) ? sh[tid - o] : 0;
        __syncthreads();
        sh[tid] += t;
        __syncthreads();
    }
    int excl = sh[tid] - v + blksum[blockIdx.x];
    if (i < M) {
        rowptr[i] = excl;
        cursor[i] = excl;
    }
    if (i == M - 1) rowptr[M] = excl + v;
}

__global__ __launch_bounds__(256) void fill_k(const int* __restrict__ src,
                                              const int* __restrict__ dst, int E,
                                              int* __restrict__ cursor,
                                              int* __restrict__ col) {
    int e = blockIdx.x * 256 + threadIdx.x;
    if (e >= E) return;
    int d = dst[e];
    int slot = atomicAdd(&cursor[d], 1);
    col[slot] = src[e];
}

// ---- GEMM: C[M,N] = X[M,128] @ W[128,N]  (f32, cache-served W) ------------
template <int N>
__global__ __launch_bounds__(256) void gemm_xw(const float* __restrict__ X,
                                               const float* __restrict__ W,
                                               float* __restrict__ C, int M) {
    constexpr int NG = N / 8;        // thread cols groups
    constexpr int MT = 256 / NG;     // threads along M
    constexpr int BM = MT * 4;       // rows per block
    const int tn = threadIdx.x % NG;
    const int tm = threadIdx.x / NG;
    const int c0 = tn * 8;
    const int r0 = blockIdx.x * BM + tm * 4;
    if (r0 >= M) return;
    const int rmax = M - 1;
    float acc[4][8];
#pragma unroll
    for (int r = 0; r < 4; r++)
#pragma unroll
        for (int c = 0; c < 8; c++) acc[r][c] = 0.f;

    for (int k = 0; k < 128; k += 4) {
        float w[4][8];
#pragma unroll
        for (int kk = 0; kk < 4; kk++) {
            float4 a = *(const float4*)&W[(size_t)(k + kk) * N + c0];
            float4 b = *(const float4*)&W[(size_t)(k + kk) * N + c0 + 4];
            w[kk][0] = a.x; w[kk][1] = a.y; w[kk][2] = a.z; w[kk][3] = a.w;
            w[kk][4] = b.x; w[kk][5] = b.y; w[kk][6] = b.z; w[kk][7] = b.w;
        }
#pragma unroll
        for (int r = 0; r < 4; r++) {
            int rr = r0 + r;
            rr = rr > rmax ? rmax : rr;
            float4 xv = *(const float4*)&X[(size_t)rr * 128 + k];
#pragma unroll
            for (int c = 0; c < 8; c++) {
                acc[r][c] = fmaf(xv.x, w[0][c], acc[r][c]);
                acc[r][c] = fmaf(xv.y, w[1][c], acc[r][c]);
                acc[r][c] = fmaf(xv.z, w[2][c], acc[r][c]);
                acc[r][c] = fmaf(xv.w, w[3][c], acc[r][c]);
            }
        }
    }
#pragma unroll
    for (int r = 0; r < 4; r++) {
        if (r0 + r < M) {
            float4 o0 = {acc[r][0], acc[r][1], acc[r][2], acc[r][3]};
            float4 o1 = {acc[r][4], acc[r][5], acc[r][6], acc[r][7]};
            *(float4*)&C[(size_t)(r0 + r) * N + c0] = o0;
            *(float4*)&C[(size_t)(r0 + r) * N + c0 + 4] = o1;
        }
    }
}

// ---- aggregation, F=128: one wave per node, float2 per lane ---------------
__global__ __launch_bounds__(256) void agg128_k(const float* __restrict__ H,
                                                const int* __restrict__ rowptr,
                                                const int* __restrict__ col,
                                                const float* __restrict__ dinv,
                                                const float* __restrict__ bias,
                                                float* __restrict__ out, int M,
                                                int relu) {
    int node = blockIdx.x * 4 + (threadIdx.x >> 6);
    if (node >= M) return;
    int lane = threadIdx.x & 63;
    const float di = dinv[node];
    float2 hs = *(const float2*)&H[(size_t)node * 128 + lane * 2];
    float ax = di * di * hs.x;
    float ay = di * di * hs.y;
    int s = rowptr[node], e = rowptr[node + 1];
    int i = s;
    int n4 = s + ((e - s) & ~3);
    for (; i < n4; i += 4) {
        int s0 = col[i], s1 = col[i + 1], s2 = col[i + 2], s3 = col[i + 3];
        float w0 = di * dinv[s0], w1 = di * dinv[s1];
        float w2 = di * dinv[s2], w3 = di * dinv[s3];
        float2 h0 = *(const float2*)&H[(size_t)s0 * 128 + lane * 2];
        float2 h1 = *(const float2*)&H[(size_t)s1 * 128 + lane * 2];
        float2 h2 = *(const float2*)&H[(size_t)s2 * 128 + lane * 2];
        float2 h3 = *(const float2*)&H[(size_t)s3 * 128 + lane * 2];
        ax = fmaf(w0, h0.x, ax); ay = fmaf(w0, h0.y, ay);
        ax = fmaf(w1, h1.x, ax); ay = fmaf(w1, h1.y, ay);
        ax = fmaf(w2, h2.x, ax); ay = fmaf(w2, h2.y, ay);
        ax = fmaf(w3, h3.x, ax); ay = fmaf(w3, h3.y, ay);
    }
    for (; i < e; i++) {
        int s0 = col[i];
        float w0 = di * dinv[s0];
        float2 h0 = *(const float2*)&H[(size_t)s0 * 128 + lane * 2];
        ax = fmaf(w0, h0.x, ax); ay = fmaf(w0, h0.y, ay);
    }
    float2 bv = *(const float2*)&bias[lane * 2];
    float ox = ax + bv.x, oy = ay + bv.y;
    if (relu) { ox = fmaxf(ox, 0.f); oy = fmaxf(oy, 0.f); }
    *(float2*)&out[(size_t)node * 128 + lane * 2] = make_float2(ox, oy);
}

// ---- aggregation, F=32: wave per node, edge list split over lane halves ---
__global__ __launch_bounds__(256) void agg32_k(const float* __restrict__ H,
                                               const int* __restrict__ rowptr,
                                               const int* __restrict__ col,
                                               const float* __restrict__ dinv,
                                               const float* __restrict__ bias,
                                               float* __restrict__ out, int M) {
    int node = blockIdx.x * 4 + (threadIdx.x >> 6);
    if (node >= M) return;
    int lane = threadIdx.x & 63;
    int f = lane & 31;
    int half = lane >> 5;
    const float di = dinv[node];
    float acc = 0.f;
    if (!half) acc = di * di * H[(size_t)node * 32 + f];
    int s = rowptr[node], e = rowptr[node + 1];
    for (int i = s + half; i < e; i += 2) {
        int s0 = col[i];
        acc = fmaf(di * dinv[s0], H[(size_t)s0 * 32 + f], acc);
    }
    acc += __shfl_xor(acc, 32);
    if (!half) out[(size_t)node * 32 + f] = acc + bias[f];
}

// ---- global mean pool over sorted batch ids -------------------------------
__global__ __launch_bounds__(256) void pool_k(const float* __restrict__ h,
                                              const int* __restrict__ batch, int M,
                                              float* __restrict__ out) {
    int g = blockIdx.x;
    int lo, hi;
    {
        int l = 0, r = M;
        while (l < r) { int m = (l + r) >> 1; if (batch[m] < g) l = m + 1; else r = m; }
        lo = l;
    }
    {
        int l = lo, r = M;
        while (l < r) { int m = (l + r) >> 1; if (batch[m] < g + 1) l = m + 1; else r = m; }
        hi = l;
    }
    int f = threadIdx.x & 31;
    int chunk = threadIdx.x >> 5;  // 8 chunks
    float acc = 0.f;
    for (int i = lo + chunk; i < hi; i += 8) acc += h[(size_t)i * 32 + f];
    __shared__ float red[8][32];
    red[chunk][f] = acc;
    __syncthreads();
    if (threadIdx.x < 32) {
        float s = 0.f;
#pragma unroll
        for (int c = 0; c < 8; c++) s += red[c][f];
        out[g * 32 + f] = s / fmaxf((float)(hi - lo), 1.f);
    }
}

extern "C" void kernel_launch(void* const* d_in, const int* in_sizes, int n_in,
                              void* d_out, int out_size, void* d_ws, size_t ws_size,
                              hipStream_t stream) {
    const float* x   = (const float*)d_in[0];
    const int* ei    = (const int*)d_in[1];
    const int* batch = (const int*)d_in[2];
    const float* W1  = (const float*)d_in[4];
    const float* b1  = (const float*)d_in[5];
    const float* W2  = (const float*)d_in[6];
    const float* b2  = (const float*)d_in[7];
    const float* W3  = (const float*)d_in[8];
    const float* b3  = (const float*)d_in[9];

    const int M = in_sizes[0] / 128;
    const int E = in_sizes[1] / 2;
    const int G = 64;  // N_GRAPHS (problem constant)
    const int* srcp = ei;
    const int* dstp = ei + E;

    // workspace carve (256B aligned)
    char* p = (char*)d_ws;
    auto carve = [&](size_t bytes) {
        void* r = (void*)p;
        p += (bytes + 255) & ~(size_t)255;
        return r;
    };
    int*   deg    = (int*)carve((size_t)M * 4);
    float* dinv   = (float*)carve((size_t)M * 4);
    int*   rowptr = (int*)carve((size_t)(M + 1) * 4);
    int*   cursor = (int*)carve((size_t)M * 4);
    int*   blksum = (int*)carve(512 * 4);
    int*   col    = (int*)carve((size_t)E * 4);
    float* bufA   = (float*)carve((size_t)M * 128 * 4);
    float* bufB   = (float*)carve((size_t)M * 128 * 4);

    float* outh = (float*)d_out;             // [M,32]
    float* outg = outh + (size_t)M * 32;     // [G,32]

    const int nbM = (M + 255) / 256;
    const int nbE = (E + 255) / 256;

    initdeg_k<<<nbM, 256, 0, stream>>>(deg, M);
    count_k<<<nbE, 256, 0, stream>>>(dstp, E, deg);
    mkdinv_k<<<nbM, 256, 0, stream>>>(deg, dinv, M);
    scan1_k<<<nbM, 256, 0, stream>>>(deg, M, blksum);
    scan2_k<<<1, 512, 0, stream>>>(blksum, nbM);
    scan3_k<<<nbM, 256, 0, stream>>>(deg, M, blksum, rowptr, cursor);
    fill_k<<<nbE, 256, 0, stream>>>(srcp, dstp, E, cursor, col);

    // layer 1: x @ W1 -> A ; agg A -> B (relu)
    gemm_xw<128><<<(M + 63) / 64, 256, 0, stream>>>(x, W1, bufA, M);
    agg128_k<<<(M + 3) / 4, 256, 0, stream>>>(bufA, rowptr, col, dinv, b1, bufB, M, 1);
    // layer 2: B @ W2 -> A ; agg A -> B (relu)
    gemm_xw<128><<<(M + 63) / 64, 256, 0, stream>>>(bufB, W2, bufA, M);
    agg128_k<<<(M + 3) / 4, 256, 0, stream>>>(bufA, rowptr, col, dinv, b2, bufB, M, 1);
    // layer 3: B @ W3 -> A[:,:32] ; agg A -> d_out (no relu)
    gemm_xw<32><<<(M + 255) / 256, 256, 0, stream>>>(bufB, W3, bufA, M);
    agg32_k<<<(M + 3) / 4, 256, 0, stream>>>(bufA, rowptr, col, dinv, b3, outh, M);
    // pool
    pool_k<<<G, 256, 0, stream>>>(outh, batch, M, outg);
}

// Round 2
// 883.566 us; speedup vs baseline: 1.0499x; 1.0499x over previous
//
#include <hip/hip_runtime.h>
#include <hip/hip_bf16.h>

// ---------------------------------------------------------------------------
// SupplyChainGNN: 3-layer GCN (PyG GCNConv semantics) + global mean pool.
//   deg[i]   = 1 + indeg(i)  (self loops added)
//   dinv     = rsqrt(deg)
//   layer:   h = x @ W;  out[i] = sum_{e: dst=i} dinv[src]*dinv[i]*h[src]
//                                + dinv[i]^2 * h[i] + b;  (ReLU on layers 1,2)
// CSR (by dst) is rebuilt on-device every call (workspace is re-poisoned).
//
// R1: fill_k rewritten as range-partitioned scatter (blockIdx%8 ~ XCD
// affinity) so col[] stores merge to full lines in one XCD's L2 instead of
// 105 MB of partial-line fabric writes (was 16x write amplification).
// ---------------------------------------------------------------------------

__global__ __launch_bounds__(256) void initdeg_k(int* deg, int M) {
    int i = blockIdx.x * 256 + threadIdx.x;
    if (i < M) deg[i] = 1;  // self loop
}

__global__ __launch_bounds__(256) void count_k(const int* __restrict__ dst, int E,
                                               int* __restrict__ deg) {
    int e = blockIdx.x * 256 + threadIdx.x;
    if (e < E) atomicAdd(&deg[dst[e]], 1);
}

__global__ __launch_bounds__(256) void mkdinv_k(const int* __restrict__ deg,
                                                float* __restrict__ dinv, int M) {
    int i = blockIdx.x * 256 + threadIdx.x;
    if (i < M) dinv[i] = rsqrtf((float)deg[i]);
}

// ---- block-scan of edge counts (deg-1) to build rowptr --------------------
__global__ __launch_bounds__(256) void scan1_k(const int* __restrict__ deg, int M,
                                               int* __restrict__ blksum) {
    __shared__ int sh[256];
    int i = blockIdx.x * 256 + threadIdx.x;
    int v = (i < M) ? deg[i] - 1 : 0;
    sh[threadIdx.x] = v;
    __syncthreads();
    for (int o = 128; o > 0; o >>= 1) {
        if (threadIdx.x < o) sh[threadIdx.x] += sh[threadIdx.x + o];
        __syncthreads();
    }
    if (threadIdx.x == 0) blksum[blockIdx.x] = sh[0];
}

__global__ __launch_bounds__(512) void scan2_k(int* __restrict__ blksum, int nb) {
    // single block, exclusive scan of up to 512 block sums (Hillis-Steele)
    __shared__ int sh[512];
    int tid = threadIdx.x;
    int v = (tid < nb) ? blksum[tid] : 0;
    sh[tid] = v;
    __syncthreads();
    for (int o = 1; o < 512; o <<= 1) {
        int t = (tid >= o) ? sh[tid - o] : 0;
        __syncthreads();
        sh[tid] += t;
        __syncthreads();
    }
    if (tid < nb) blksum[tid] = sh[tid] - v;  // exclusive
}

__global__ __launch_bounds__(256) void scan3_k(const int* __restrict__ deg, int M,
                                               const int* __restrict__ blksum,
                                               int* __restrict__ rowptr,
                                               int* __restrict__ cursor) {
    __shared__ int sh[256];
    int tid = threadIdx.x;
    int i = blockIdx.x * 256 + tid;
    int v = (i < M) ? deg[i] - 1 : 0;
    sh[tid] = v;
    __syncthreads();
    for (int o = 1; o < 256; o <<= 1) {
        int t = (tid >= o) ? sh[tid - o] : 0;
        __syncthreads();
        sh[tid] += t;
        __syncthreads();
    }
    int excl = sh[tid] - v + blksum[blockIdx.x];
    if (i < M) {
        rowptr[i] = excl;
        cursor[i] = excl;
    }
    if (i == M - 1) rowptr[M] = excl + v;
}

// ---- CSR slot fill, dst-range partitioned for XCD-local col[] writes ------
// blocks with blockIdx%8 == r handle only dst in node-range r; the %8 maps to
// the XCD round-robin dispatch, so each col[] region is written by one XCD's
// L2 -> full-line merging instead of per-store partial-line fabric writes.
#define FILL_CHUNK 4096
__global__ __launch_bounds__(256) void fill_rp_k(const int* __restrict__ src,
                                                 const int* __restrict__ dst,
                                                 int E, int M,
                                                 int* __restrict__ cursor,
                                                 int* __restrict__ col) {
    const int r = blockIdx.x & 7;
    const int chunk = blockIdx.x >> 3;
    const int lo = (int)(((long long)r * M) >> 3);
    const int hi = (int)(((long long)(r + 1) * M) >> 3);
    const int base = chunk * FILL_CHUNK;
    const int end = min(E, base + FILL_CHUNK);
    for (int e = base + (int)threadIdx.x; e < end; e += 256) {
        int d = dst[e];
        int s = src[e];  // unconditional coalesced load
        if (d >= lo && d < hi) {
            int slot = atomicAdd(&cursor[d], 1);
            col[slot] = s;
        }
    }
}

// ---- GEMM: C[M,N] = X[M,128] @ W[128,N]  (f32, cache-served W) ------------
template <int N>
__global__ __launch_bounds__(256) void gemm_xw(const float* __restrict__ X,
                                               const float* __restrict__ W,
                                               float* __restrict__ C, int M) {
    constexpr int NG = N / 8;        // thread cols groups
    constexpr int MT = 256 / NG;     // threads along M
    constexpr int BM = MT * 4;       // rows per block
    const int tn = threadIdx.x % NG;
    const int tm = threadIdx.x / NG;
    const int c0 = tn * 8;
    const int r0 = blockIdx.x * BM + tm * 4;
    if (r0 >= M) return;
    const int rmax = M - 1;
    float acc[4][8];
#pragma unroll
    for (int r = 0; r < 4; r++)
#pragma unroll
        for (int c = 0; c < 8; c++) acc[r][c] = 0.f;

    for (int k = 0; k < 128; k += 4) {
        float w[4][8];
#pragma unroll
        for (int kk = 0; kk < 4; kk++) {
            float4 a = *(const float4*)&W[(size_t)(k + kk) * N + c0];
            float4 b = *(const float4*)&W[(size_t)(k + kk) * N + c0 + 4];
            w[kk][0] = a.x; w[kk][1] = a.y; w[kk][2] = a.z; w[kk][3] = a.w;
            w[kk][4] = b.x; w[kk][5] = b.y; w[kk][6] = b.z; w[kk][7] = b.w;
        }
#pragma unroll
        for (int r = 0; r < 4; r++) {
            int rr = r0 + r;
            rr = rr > rmax ? rmax : rr;
            float4 xv = *(const float4*)&X[(size_t)rr * 128 + k];
#pragma unroll
            for (int c = 0; c < 8; c++) {
                acc[r][c] = fmaf(xv.x, w[0][c], acc[r][c]);
                acc[r][c] = fmaf(xv.y, w[1][c], acc[r][c]);
                acc[r][c] = fmaf(xv.z, w[2][c], acc[r][c]);
                acc[r][c] = fmaf(xv.w, w[3][c], acc[r][c]);
            }
        }
    }
#pragma unroll
    for (int r = 0; r < 4; r++) {
        if (r0 + r < M) {
            float4 o0 = {acc[r][0], acc[r][1], acc[r][2], acc[r][3]};
            float4 o1 = {acc[r][4], acc[r][5], acc[r][6], acc[r][7]};
            *(float4*)&C[(size_t)(r0 + r) * N + c0] = o0;
            *(float4*)&C[(size_t)(r0 + r) * N + c0 + 4] = o1;
        }
    }
}

// ---- aggregation, F=128: one wave per node, float2 per lane ---------------
__global__ __launch_bounds__(256) void agg128_k(const float* __restrict__ H,
                                                const int* __restrict__ rowptr,
                                                const int* __restrict__ col,
                                                const float* __restrict__ dinv,
                                                const float* __restrict__ bias,
                                                float* __restrict__ out, int M,
                                                int relu) {
    int node = blockIdx.x * 4 + (threadIdx.x >> 6);
    if (node >= M) return;
    int lane = threadIdx.x & 63;
    const float di = dinv[node];
    float2 hs = *(const float2*)&H[(size_t)node * 128 + lane * 2];
    float ax = di * di * hs.x;
    float ay = di * di * hs.y;
    int s = rowptr[node], e = rowptr[node + 1];
    int i = s;
    int n4 = s + ((e - s) & ~3);
    for (; i < n4; i += 4) {
        int s0 = col[i], s1 = col[i + 1], s2 = col[i + 2], s3 = col[i + 3];
        float w0 = di * dinv[s0], w1 = di * dinv[s1];
        float w2 = di * dinv[s2], w3 = di * dinv[s3];
        float2 h0 = *(const float2*)&H[(size_t)s0 * 128 + lane * 2];
        float2 h1 = *(const float2*)&H[(size_t)s1 * 128 + lane * 2];
        float2 h2 = *(const float2*)&H[(size_t)s2 * 128 + lane * 2];
        float2 h3 = *(const float2*)&H[(size_t)s3 * 128 + lane * 2];
        ax = fmaf(w0, h0.x, ax); ay = fmaf(w0, h0.y, ay);
        ax = fmaf(w1, h1.x, ax); ay = fmaf(w1, h1.y, ay);
        ax = fmaf(w2, h2.x, ax); ay = fmaf(w2, h2.y, ay);
        ax = fmaf(w3, h3.x, ax); ay = fmaf(w3, h3.y, ay);
    }
    for (; i < e; i++) {
        int s0 = col[i];
        float w0 = di * dinv[s0];
        float2 h0 = *(const float2*)&H[(size_t)s0 * 128 + lane * 2];
        ax = fmaf(w0, h0.x, ax); ay = fmaf(w0, h0.y, ay);
    }
    float2 bv = *(const float2*)&bias[lane * 2];
    float ox = ax + bv.x, oy = ay + bv.y;
    if (relu) { ox = fmaxf(ox, 0.f); oy = fmaxf(oy, 0.f); }
    *(float2*)&out[(size_t)node * 128 + lane * 2] = make_float2(ox, oy);
}

// ---- aggregation, F=32: wave per node, edge list split over lane halves ---
__global__ __launch_bounds__(256) void agg32_k(const float* __restrict__ H,
                                               const int* __restrict__ rowptr,
                                               const int* __restrict__ col,
                                               const float* __restrict__ dinv,
                                               const float* __restrict__ bias,
                                               float* __restrict__ out, int M) {
    int node = blockIdx.x * 4 + (threadIdx.x >> 6);
    if (node >= M) return;
    int lane = threadIdx.x & 63;
    int f = lane & 31;
    int half = lane >> 5;
    const float di = dinv[node];
    float acc = 0.f;
    if (!half) acc = di * di * H[(size_t)node * 32 + f];
    int s = rowptr[node], e = rowptr[node + 1];
    for (int i = s + half; i < e; i += 2) {
        int s0 = col[i];
        acc = fmaf(di * dinv[s0], H[(size_t)s0 * 32 + f], acc);
    }
    acc += __shfl_xor(acc, 32);
    if (!half) out[(size_t)node * 32 + f] = acc + bias[f];
}

// ---- global mean pool over sorted batch ids -------------------------------
__global__ __launch_bounds__(256) void pool_k(const float* __restrict__ h,
                                              const int* __restrict__ batch, int M,
                                              float* __restrict__ out) {
    int g = blockIdx.x;
    int lo, hi;
    {
        int l = 0, r = M;
        while (l < r) { int m = (l + r) >> 1; if (batch[m] < g) l = m + 1; else r = m; }
        lo = l;
    }
    {
        int l = lo, r = M;
        while (l < r) { int m = (l + r) >> 1; if (batch[m] < g + 1) l = m + 1; else r = m; }
        hi = l;
    }
    int f = threadIdx.x & 31;
    int chunk = threadIdx.x >> 5;  // 8 chunks
    float acc = 0.f;
    for (int i = lo + chunk; i < hi; i += 8) acc += h[(size_t)i * 32 + f];
    __shared__ float red[8][32];
    red[chunk][f] = acc;
    __syncthreads();
    if (threadIdx.x < 32) {
        float s = 0.f;
#pragma unroll
        for (int c = 0; c < 8; c++) s += red[c][f];
        out[g * 32 + f] = s / fmaxf((float)(hi - lo), 1.f);
    }
}

extern "C" void kernel_launch(void* const* d_in, const int* in_sizes, int n_in,
                              void* d_out, int out_size, void* d_ws, size_t ws_size,
                              hipStream_t stream) {
    const float* x   = (const float*)d_in[0];
    const int* ei    = (const int*)d_in[1];
    const int* batch = (const int*)d_in[2];
    const float* W1  = (const float*)d_in[4];
    const float* b1  = (const float*)d_in[5];
    const float* W2  = (const float*)d_in[6];
    const float* b2  = (const float*)d_in[7];
    const float* W3  = (const float*)d_in[8];
    const float* b3  = (const float*)d_in[9];

    const int M = in_sizes[0] / 128;
    const int E = in_sizes[1] / 2;
    const int G = 64;  // N_GRAPHS (problem constant)
    const int* srcp = ei;
    const int* dstp = ei + E;

    // workspace carve (256B aligned)
    char* p = (char*)d_ws;
    auto carve = [&](size_t bytes) {
        void* r = (void*)p;
        p += (bytes + 255) & ~(size_t)255;
        return r;
    };
    int*   deg    = (int*)carve((size_t)M * 4);
    float* dinv   = (float*)carve((size_t)M * 4);
    int*   rowptr = (int*)carve((size_t)(M + 1) * 4);
    int*   cursor = (int*)carve((size_t)M * 4);
    int*   blksum = (int*)carve(512 * 4);
    int*   col    = (int*)carve((size_t)E * 4);
    float* bufA   = (float*)carve((size_t)M * 128 * 4);
    float* bufB   = (float*)carve((size_t)M * 128 * 4);

    float* outh = (float*)d_out;             // [M,32]
    float* outg = outh + (size_t)M * 32;     // [G,32]

    const int nbM = (M + 255) / 256;
    const int nbE = (E + 255) / 256;

    initdeg_k<<<nbM, 256, 0, stream>>>(deg, M);
    count_k<<<nbE, 256, 0, stream>>>(dstp, E, deg);
    mkdinv_k<<<nbM, 256, 0, stream>>>(deg, dinv, M);
    scan1_k<<<nbM, 256, 0, stream>>>(deg, M, blksum);
    scan2_k<<<1, 512, 0, stream>>>(blksum, nbM);
    scan3_k<<<nbM, 256, 0, stream>>>(deg, M, blksum, rowptr, cursor);
    {
        const int nchunk = (E + FILL_CHUNK - 1) / FILL_CHUNK;
        fill_rp_k<<<nchunk * 8, 256, 0, stream>>>(srcp, dstp, E, M, cursor, col);
    }

    // layer 1: x @ W1 -> A ; agg A -> B (relu)
    gemm_xw<128><<<(M + 63) / 64, 256, 0, stream>>>(x, W1, bufA, M);
    agg128_k<<<(M + 3) / 4, 256, 0, stream>>>(bufA, rowptr, col, dinv, b1, bufB, M, 1);
    // layer 2: B @ W2 -> A ; agg A -> B (relu)
    gemm_xw<128><<<(M + 63) / 64, 256, 0, stream>>>(bufB, W2, bufA, M);
    agg128_k<<<(M + 3) / 4, 256, 0, stream>>>(bufA, rowptr, col, dinv, b2, bufB, M, 1);
    // layer 3: B @ W3 -> A[:,:32] ; agg A -> d_out (no relu)
    gemm_xw<32><<<(M + 255) / 256, 256, 0, stream>>>(bufB, W3, bufA, M);
    agg32_k<<<(M + 3) / 4, 256, 0, stream>>>(bufA, rowptr, col, dinv, b3, outh, M);
    // pool
    pool_k<<<G, 256, 0, stream>>>(outh, batch, M, outg);
}

// Round 3
// 719.589 us; speedup vs baseline: 1.2891x; 1.2279x over previous
//
#include <hip/hip_runtime.h>
#include <hip/hip_bf16.h>

// ---------------------------------------------------------------------------
// SupplyChainGNN: 3-layer GCN (PyG GCNConv semantics) + global mean pool.
//   deg[i]   = 1 + indeg(i)  (self loops added)
//   dinv     = rsqrt(deg)
//   layer:   h = x @ W (bf16-stored);  out[i] = sum_{e} dinv[s]*dinv[i]*h[s]
//                                + dinv[i]^2 * h[i] + b;  (ReLU on layers 1,2)
// CSR (by dst) is rebuilt on-device every call (workspace is re-poisoned).
//
// R1: fill range-partitioned (blockIdx%8 ~ XCD) -> full-line col[] writes.
// R2: H stored bf16 (halves the 415MB cross-fabric gather fetch: every XCD
//     structurally touches ~all of H) + chunk-cooperative col/dinv loading
//     with 8-deep gather pipelining in agg128 (was 3-deep dependent chain).
// ---------------------------------------------------------------------------

typedef unsigned int uint32;
typedef unsigned short ushort16;

static __device__ __forceinline__ unsigned short f2bf(float f) {
    uint32 u = __float_as_uint(f);
    return (unsigned short)((u + 0x7fffu + ((u >> 16) & 1u)) >> 16);  // RNE
}
static __device__ __forceinline__ float bf2f_lo(uint32 u) {
    return __uint_as_float(u << 16);
}
static __device__ __forceinline__ float bf2f_hi(uint32 u) {
    return __uint_as_float(u & 0xffff0000u);
}

__global__ __launch_bounds__(256) void initdeg_k(int* deg, int M) {
    int i = blockIdx.x * 256 + threadIdx.x;
    if (i < M) deg[i] = 1;  // self loop
}

__global__ __launch_bounds__(256) void count_k(const int* __restrict__ dst, int E,
                                               int* __restrict__ deg) {
    int e = blockIdx.x * 256 + threadIdx.x;
    if (e < E) atomicAdd(&deg[dst[e]], 1);
}

__global__ __launch_bounds__(256) void mkdinv_k(const int* __restrict__ deg,
                                                float* __restrict__ dinv, int M) {
    int i = blockIdx.x * 256 + threadIdx.x;
    if (i < M) dinv[i] = rsqrtf((float)deg[i]);
}

// ---- block-scan of edge counts (deg-1) to build rowptr --------------------
__global__ __launch_bounds__(256) void scan1_k(const int* __restrict__ deg, int M,
                                               int* __restrict__ blksum) {
    __shared__ int sh[256];
    int i = blockIdx.x * 256 + threadIdx.x;
    int v = (i < M) ? deg[i] - 1 : 0;
    sh[threadIdx.x] = v;
    __syncthreads();
    for (int o = 128; o > 0; o >>= 1) {
        if (threadIdx.x < o) sh[threadIdx.x] += sh[threadIdx.x + o];
        __syncthreads();
    }
    if (threadIdx.x == 0) blksum[blockIdx.x] = sh[0];
}

__global__ __launch_bounds__(512) void scan2_k(int* __restrict__ blksum, int nb) {
    __shared__ int sh[512];
    int tid = threadIdx.x;
    int v = (tid < nb) ? blksum[tid] : 0;
    sh[tid] = v;
    __syncthreads();
    for (int o = 1; o < 512; o <<= 1) {
        int t = (tid >= o) ? sh[tid - o] : 0;
        __syncthreads();
        sh[tid] += t;
        __syncthreads();
    }
    if (tid < nb) blksum[tid] = sh[tid] - v;  // exclusive
}

__global__ __launch_bounds__(256) void scan3_k(const int* __restrict__ deg, int M,
                                               const int* __restrict__ blksum,
                                               int* __restrict__ rowptr,
                                               int* __restrict__ cursor) {
    __shared__ int sh[256];
    int tid = threadIdx.x;
    int i = blockIdx.x * 256 + tid;
    int v = (i < M) ? deg[i] - 1 : 0;
    sh[tid] = v;
    __syncthreads();
    for (int o = 1; o < 256; o <<= 1) {
        int t = (tid >= o) ? sh[tid - o] : 0;
        __syncthreads();
        sh[tid] += t;
        __syncthreads();
    }
    int excl = sh[tid] - v + blksum[blockIdx.x];
    if (i < M) {
        rowptr[i] = excl;
        cursor[i] = excl;
    }
    if (i == M - 1) rowptr[M] = excl + v;
}

// ---- CSR slot fill, dst-range partitioned for XCD-local col[] writes ------
#define FILL_CHUNK 4096
__global__ __launch_bounds__(256) void fill_rp_k(const int* __restrict__ src,
                                                 const int* __restrict__ dst,
                                                 int E, int M,
                                                 int* __restrict__ cursor,
                                                 int* __restrict__ col) {
    const int r = blockIdx.x & 7;
    const int chunk = blockIdx.x >> 3;
    const int lo = (int)(((long long)r * M) >> 3);
    const int hi = (int)(((long long)(r + 1) * M) >> 3);
    const int base = chunk * FILL_CHUNK;
    const int end = min(E, base + FILL_CHUNK);
    for (int e = base + (int)threadIdx.x; e < end; e += 256) {
        int d = dst[e];
        int s = src[e];
        if (d >= lo && d < hi) {
            int slot = atomicAdd(&cursor[d], 1);
            col[slot] = s;
        }
    }
}

// ---- GEMM: C[M,N](bf16) = X[M,128](f32) @ W[128,N](f32) -------------------
template <int N>
__global__ __launch_bounds__(256) void gemm_bf(const float* __restrict__ X,
                                               const float* __restrict__ W,
                                               unsigned short* __restrict__ C,
                                               int M) {
    constexpr int NG = N / 8;
    constexpr int MT = 256 / NG;
    constexpr int BM = MT * 4;
    const int tn = threadIdx.x % NG;
    const int tm = threadIdx.x / NG;
    const int c0 = tn * 8;
    const int r0 = blockIdx.x * BM + tm * 4;
    if (r0 >= M) return;
    const int rmax = M - 1;
    float acc[4][8];
#pragma unroll
    for (int r = 0; r < 4; r++)
#pragma unroll
        for (int c = 0; c < 8; c++) acc[r][c] = 0.f;

    for (int k = 0; k < 128; k += 4) {
        float w[4][8];
#pragma unroll
        for (int kk = 0; kk < 4; kk++) {
            float4 a = *(const float4*)&W[(size_t)(k + kk) * N + c0];
            float4 b = *(const float4*)&W[(size_t)(k + kk) * N + c0 + 4];
            w[kk][0] = a.x; w[kk][1] = a.y; w[kk][2] = a.z; w[kk][3] = a.w;
            w[kk][4] = b.x; w[kk][5] = b.y; w[kk][6] = b.z; w[kk][7] = b.w;
        }
#pragma unroll
        for (int r = 0; r < 4; r++) {
            int rr = r0 + r;
            rr = rr > rmax ? rmax : rr;
            float4 xv = *(const float4*)&X[(size_t)rr * 128 + k];
#pragma unroll
            for (int c = 0; c < 8; c++) {
                acc[r][c] = fmaf(xv.x, w[0][c], acc[r][c]);
                acc[r][c] = fmaf(xv.y, w[1][c], acc[r][c]);
                acc[r][c] = fmaf(xv.z, w[2][c], acc[r][c]);
                acc[r][c] = fmaf(xv.w, w[3][c], acc[r][c]);
            }
        }
    }
#pragma unroll
    for (int r = 0; r < 4; r++) {
        if (r0 + r < M) {
            union { unsigned short us[8]; uint4 v4; } cv;
#pragma unroll
            for (int c = 0; c < 8; c++) cv.us[c] = f2bf(acc[r][c]);
            *(uint4*)&C[(size_t)(r0 + r) * N + c0] = cv.v4;
        }
    }
}

// ---- aggregation, F=128 (bf16 H): wave/node, chunked edges, 8-deep gathers
__global__ __launch_bounds__(256) void agg128_k(const unsigned short* __restrict__ Hb,
                                                const int* __restrict__ rowptr,
                                                const int* __restrict__ col,
                                                const float* __restrict__ dinv,
                                                const float* __restrict__ bias,
                                                float* __restrict__ out, int M,
                                                int relu) {
    int node = blockIdx.x * 4 + (threadIdx.x >> 6);
    if (node >= M) return;
    int lane = threadIdx.x & 63;
    const float di = dinv[node];
    const uint32* Hu = (const uint32*)Hb;  // row = 64 uints (128 bf16)
    uint32 su = Hu[(size_t)node * 64 + lane];
    float ax = di * di * bf2f_lo(su);
    float ay = di * di * bf2f_hi(su);
    const int s = rowptr[node], e = rowptr[node + 1];

    for (int base = s; base < e; base += 64) {
        int n = e - base;
        if (n > 64) n = 64;
        int cid = col[base + (lane < n ? lane : 0)];
        float w = di * dinv[cid];
        int j = 0;
        for (; j + 8 <= n; j += 8) {
            int sj[8]; float wj[8]; uint32 u[8];
#pragma unroll
            for (int k = 0; k < 8; k++) {
                sj[k] = __shfl(cid, j + k);
                wj[k] = __shfl(w, j + k);
            }
#pragma unroll
            for (int k = 0; k < 8; k++)
                u[k] = Hu[(size_t)sj[k] * 64 + lane];
#pragma unroll
            for (int k = 0; k < 8; k++) {
                ax = fmaf(wj[k], bf2f_lo(u[k]), ax);
                ay = fmaf(wj[k], bf2f_hi(u[k]), ay);
            }
        }
        for (; j < n; j++) {
            int s0 = __shfl(cid, j);
            float w0 = __shfl(w, j);
            uint32 u0 = Hu[(size_t)s0 * 64 + lane];
            ax = fmaf(w0, bf2f_lo(u0), ax);
            ay = fmaf(w0, bf2f_hi(u0), ay);
        }
    }
    float2 bv = *(const float2*)&bias[lane * 2];
    float ox = ax + bv.x, oy = ay + bv.y;
    if (relu) { ox = fmaxf(ox, 0.f); oy = fmaxf(oy, 0.f); }
    *(float2*)&out[(size_t)node * 128 + lane * 2] = make_float2(ox, oy);
}

// ---- aggregation, F=32 (bf16 H): wave per node, halves split edge list ----
__global__ __launch_bounds__(256) void agg32_k(const unsigned short* __restrict__ Hb,
                                               const int* __restrict__ rowptr,
                                               const int* __restrict__ col,
                                               const float* __restrict__ dinv,
                                               const float* __restrict__ bias,
                                               float* __restrict__ out, int M) {
    int node = blockIdx.x * 4 + (threadIdx.x >> 6);
    if (node >= M) return;
    int lane = threadIdx.x & 63;
    int f = lane & 31;
    int half = lane >> 5;
    const float di = dinv[node];
    float acc = 0.f;
    if (!half)
        acc = di * di * __uint_as_float(((uint32)Hb[(size_t)node * 32 + f]) << 16);
    const int s = rowptr[node], e = rowptr[node + 1];
    int i = s + half;
    for (; i + 6 < e; i += 8) {
        int s0 = col[i], s1 = col[i + 2], s2 = col[i + 4], s3 = col[i + 6];
        float w0 = di * dinv[s0], w1 = di * dinv[s1];
        float w2 = di * dinv[s2], w3 = di * dinv[s3];
        float h0 = __uint_as_float(((uint32)Hb[(size_t)s0 * 32 + f]) << 16);
        float h1 = __uint_as_float(((uint32)Hb[(size_t)s1 * 32 + f]) << 16);
        float h2 = __uint_as_float(((uint32)Hb[(size_t)s2 * 32 + f]) << 16);
        float h3 = __uint_as_float(((uint32)Hb[(size_t)s3 * 32 + f]) << 16);
        acc = fmaf(w0, h0, acc);
        acc = fmaf(w1, h1, acc);
        acc = fmaf(w2, h2, acc);
        acc = fmaf(w3, h3, acc);
    }
    for (; i < e; i += 2) {
        int s0 = col[i];
        float h0 = __uint_as_float(((uint32)Hb[(size_t)s0 * 32 + f]) << 16);
        acc = fmaf(di * dinv[s0], h0, acc);
    }
    acc += __shfl_xor(acc, 32);
    if (!half) out[(size_t)node * 32 + f] = acc + bias[f];
}

// ---- global mean pool over sorted batch ids -------------------------------
__global__ __launch_bounds__(256) void pool_k(const float* __restrict__ h,
                                              const int* __restrict__ batch, int M,
                                              float* __restrict__ out) {
    int g = blockIdx.x;
    int lo, hi;
    {
        int l = 0, r = M;
        while (l < r) { int m = (l + r) >> 1; if (batch[m] < g) l = m + 1; else r = m; }
        lo = l;
    }
    {
        int l = lo, r = M;
        while (l < r) { int m = (l + r) >> 1; if (batch[m] < g + 1) l = m + 1; else r = m; }
        hi = l;
    }
    int f = threadIdx.x & 31;
    int chunk = threadIdx.x >> 5;  // 8 chunks
    float acc = 0.f;
    for (int i = lo + chunk; i < hi; i += 8) acc += h[(size_t)i * 32 + f];
    __shared__ float red[8][32];
    red[chunk][f] = acc;
    __syncthreads();
    if (threadIdx.x < 32) {
        float s = 0.f;
#pragma unroll
        for (int c = 0; c < 8; c++) s += red[c][f];
        out[g * 32 + f] = s / fmaxf((float)(hi - lo), 1.f);
    }
}

extern "C" void kernel_launch(void* const* d_in, const int* in_sizes, int n_in,
                              void* d_out, int out_size, void* d_ws, size_t ws_size,
                              hipStream_t stream) {
    const float* x   = (const float*)d_in[0];
    const int* ei    = (const int*)d_in[1];
    const int* batch = (const int*)d_in[2];
    const float* W1  = (const float*)d_in[4];
    const float* b1  = (const float*)d_in[5];
    const float* W2  = (const float*)d_in[6];
    const float* b2  = (const float*)d_in[7];
    const float* W3  = (const float*)d_in[8];
    const float* b3  = (const float*)d_in[9];

    const int M = in_sizes[0] / 128;
    const int E = in_sizes[1] / 2;
    const int G = 64;  // N_GRAPHS (problem constant)
    const int* srcp = ei;
    const int* dstp = ei + E;

    // workspace carve (256B aligned)
    char* p = (char*)d_ws;
    auto carve = [&](size_t bytes) {
        void* r = (void*)p;
        p += (bytes + 255) & ~(size_t)255;
        return r;
    };
    int*   deg    = (int*)carve((size_t)M * 4);
    float* dinv   = (float*)carve((size_t)M * 4);
    int*   rowptr = (int*)carve((size_t)(M + 1) * 4);
    int*   cursor = (int*)carve((size_t)M * 4);
    int*   blksum = (int*)carve(512 * 4);
    int*   col    = (int*)carve((size_t)E * 4);
    unsigned short* Hb = (unsigned short*)carve((size_t)M * 128 * 2);  // bf16 h
    float* O      = (float*)carve((size_t)M * 128 * 4);                // f32 agg out

    float* outh = (float*)d_out;             // [M,32]
    float* outg = outh + (size_t)M * 32;     // [G,32]

    const int nbM = (M + 255) / 256;
    const int nbE = (E + 255) / 256;

    initdeg_k<<<nbM, 256, 0, stream>>>(deg, M);
    count_k<<<nbE, 256, 0, stream>>>(dstp, E, deg);
    mkdinv_k<<<nbM, 256, 0, stream>>>(deg, dinv, M);
    scan1_k<<<nbM, 256, 0, stream>>>(deg, M, blksum);
    scan2_k<<<1, 512, 0, stream>>>(blksum, nbM);
    scan3_k<<<nbM, 256, 0, stream>>>(deg, M, blksum, rowptr, cursor);
    {
        const int nchunk = (E + FILL_CHUNK - 1) / FILL_CHUNK;
        fill_rp_k<<<nchunk * 8, 256, 0, stream>>>(srcp, dstp, E, M, cursor, col);
    }

    // layer 1
    gemm_bf<128><<<(M + 63) / 64, 256, 0, stream>>>(x, W1, Hb, M);
    agg128_k<<<(M + 3) / 4, 256, 0, stream>>>(Hb, rowptr, col, dinv, b1, O, M, 1);
    // layer 2
    gemm_bf<128><<<(M + 63) / 64, 256, 0, stream>>>(O, W2, Hb, M);
    agg128_k<<<(M + 3) / 4, 256, 0, stream>>>(Hb, rowptr, col, dinv, b2, O, M, 1);
    // layer 3
    gemm_bf<32><<<(M + 255) / 256, 256, 0, stream>>>(O, W3, Hb, M);
    agg32_k<<<(M + 3) / 4, 256, 0, stream>>>(Hb, rowptr, col, dinv, b3, outh, M);
    // pool
    pool_k<<<G, 256, 0, stream>>>(outh, batch, M, outg);
}

// Round 5
// 570.171 us; speedup vs baseline: 1.6269x; 1.2621x over previous
//
#include <hip/hip_runtime.h>
#include <hip/hip_bf16.h>

// ---------------------------------------------------------------------------
// SupplyChainGNN: 3-layer GCN (PyG GCNConv semantics) + global mean pool.
//   deg[i] = 1 + indeg(i);  dinv = rsqrt(deg)
//   layer: h = A @ W (bf16 MFMA);  out[i] = sum_e dinv[s]*dinv[i]*h[s]
//                               + dinv[i]^2*h[i] + b;  (ReLU layers 1,2)
// CSR (by dst) rebuilt on-device every call (workspace is re-poisoned).
//
// R1: fill range-partitioned (blockIdx%8 ~ XCD) -> full-line col[] writes.
// R2: H stored bf16 (halves cross-fabric gather fetch) + 8-deep gather pipe.
// R3: GEMMs -> mfma_f32_16x16x32_bf16. W transposed to Wt[N][128] bf16 once
//     per layer (contiguous short8 B-frags, m92 B^T pattern); W frags live in
//     VGPRs; A-frags read direct from global (lane (l&15)=row, (l>>4)=kgrp:
//     one inst = 16 full 64B lines). f32 path was latency-bound at 32 TF.
// R4: identical resubmit (R3 bench hit GPUAcquisitionTimeout; no data).
// ---------------------------------------------------------------------------

typedef unsigned int uint32;
typedef short short8 __attribute__((ext_vector_type(8)));
typedef float f32x4 __attribute__((ext_vector_type(4)));

static __device__ __forceinline__ unsigned short f2bf(float f) {
    uint32 u = __float_as_uint(f);
    return (unsigned short)((u + 0x7fffu + ((u >> 16) & 1u)) >> 16);  // RNE
}
static __device__ __forceinline__ float bf2f_lo(uint32 u) {
    return __uint_as_float(u << 16);
}
static __device__ __forceinline__ float bf2f_hi(uint32 u) {
    return __uint_as_float(u & 0xffff0000u);
}

__global__ __launch_bounds__(256) void initdeg_k(int* deg, int M) {
    int i = blockIdx.x * 256 + threadIdx.x;
    if (i < M) deg[i] = 1;  // self loop
}

__global__ __launch_bounds__(256) void count_k(const int* __restrict__ dst, int E,
                                               int* __restrict__ deg) {
    int e = blockIdx.x * 256 + threadIdx.x;
    if (e < E) atomicAdd(&deg[dst[e]], 1);
}

__global__ __launch_bounds__(256) void mkdinv_k(const int* __restrict__ deg,
                                                float* __restrict__ dinv, int M) {
    int i = blockIdx.x * 256 + threadIdx.x;
    if (i < M) dinv[i] = rsqrtf((float)deg[i]);
}

// ---- block-scan of edge counts (deg-1) to build rowptr --------------------
__global__ __launch_bounds__(256) void scan1_k(const int* __restrict__ deg, int M,
                                               int* __restrict__ blksum) {
    __shared__ int sh[256];
    int i = blockIdx.x * 256 + threadIdx.x;
    int v = (i < M) ? deg[i] - 1 : 0;
    sh[threadIdx.x] = v;
    __syncthreads();
    for (int o = 128; o > 0; o >>= 1) {
        if (threadIdx.x < o) sh[threadIdx.x] += sh[threadIdx.x + o];
        __syncthreads();
    }
    if (threadIdx.x == 0) blksum[blockIdx.x] = sh[0];
}

__global__ __launch_bounds__(512) void scan2_k(int* __restrict__ blksum, int nb) {
    __shared__ int sh[512];
    int tid = threadIdx.x;
    int v = (tid < nb) ? blksum[tid] : 0;
    sh[tid] = v;
    __syncthreads();
    for (int o = 1; o < 512; o <<= 1) {
        int t = (tid >= o) ? sh[tid - o] : 0;
        __syncthreads();
        sh[tid] += t;
        __syncthreads();
    }
    if (tid < nb) blksum[tid] = sh[tid] - v;  // exclusive
}

__global__ __launch_bounds__(256) void scan3_k(const int* __restrict__ deg, int M,
                                               const int* __restrict__ blksum,
                                               int* __restrict__ rowptr,
                                               int* __restrict__ cursor) {
    __shared__ int sh[256];
    int tid = threadIdx.x;
    int i = blockIdx.x * 256 + tid;
    int v = (i < M) ? deg[i] - 1 : 0;
    sh[tid] = v;
    __syncthreads();
    for (int o = 1; o < 256; o <<= 1) {
        int t = (tid >= o) ? sh[tid - o] : 0;
        __syncthreads();
        sh[tid] += t;
        __syncthreads();
    }
    int excl = sh[tid] - v + blksum[blockIdx.x];
    if (i < M) {
        rowptr[i] = excl;
        cursor[i] = excl;
    }
    if (i == M - 1) rowptr[M] = excl + v;
}

// ---- CSR slot fill, dst-range partitioned for XCD-local col[] writes ------
#define FILL_CHUNK 4096
__global__ __launch_bounds__(256) void fill_rp_k(const int* __restrict__ src,
                                                 const int* __restrict__ dst,
                                                 int E, int M,
                                                 int* __restrict__ cursor,
                                                 int* __restrict__ col) {
    const int r = blockIdx.x & 7;
    const int chunk = blockIdx.x >> 3;
    const int lo = (int)(((long long)r * M) >> 3);
    const int hi = (int)(((long long)(r + 1) * M) >> 3);
    const int base = chunk * FILL_CHUNK;
    const int end = min(E, base + FILL_CHUNK);
    for (int e = base + (int)threadIdx.x; e < end; e += 256) {
        int d = dst[e];
        int s = src[e];
        if (d >= lo && d < hi) {
            int slot = atomicAdd(&cursor[d], 1);
            col[slot] = s;
        }
    }
}

// ---- f32 -> bf16 convert (x input), 8 elems/thread ------------------------
__global__ __launch_bounds__(256) void cvt_k(const float* __restrict__ x,
                                             unsigned short* __restrict__ o,
                                             int n8) {
    int i = blockIdx.x * 256 + threadIdx.x;
    if (i >= n8) return;
    const float4* xp = (const float4*)x + (size_t)i * 2;
    float4 a = xp[0], b = xp[1];
    union { unsigned short us[8]; uint4 v; } u;
    u.us[0] = f2bf(a.x); u.us[1] = f2bf(a.y); u.us[2] = f2bf(a.z); u.us[3] = f2bf(a.w);
    u.us[4] = f2bf(b.x); u.us[5] = f2bf(b.y); u.us[6] = f2bf(b.z); u.us[7] = f2bf(b.w);
    *((uint4*)o + i) = u.v;
}

// ---- W[128][N] f32 -> Wt[N][128] bf16 (transpose + convert) ---------------
__global__ __launch_bounds__(256) void wt_k(const float* __restrict__ W,
                                            unsigned short* __restrict__ Wt,
                                            int N) {
    int idx = blockIdx.x * 256 + threadIdx.x;
    if (idx >= N * 128) return;
    int n = idx >> 7, k = idx & 127;
    Wt[idx] = f2bf(W[k * N + n]);
}

// ---- MFMA GEMM: C[M,N](bf16) = A[M,128](bf16) @ W, W given as Wt[N][128] --
// wave strip = 16 rows; frag: lane r=l&15 (row/col), g=l>>4 (k-group);
// A/B elem j of group g,step s <-> k = 32s+8g+j (consistent pairing => exact).
// C/D (m89-verified): col = l&15, row = 4*(l>>4) + reg.
template <int NT>  // NT 16-col tiles; N = 16*NT
__global__ __launch_bounds__(256) void mgemm_k(const unsigned short* __restrict__ A,
                                               const unsigned short* __restrict__ Wt,
                                               unsigned short* __restrict__ C,
                                               int M, int nstrips) {
    constexpr int N = NT * 16;
    const int lane = threadIdx.x & 63;
    const int wid = threadIdx.x >> 6;
    const int r = lane & 15;
    const int g = lane >> 4;

    short8 wf[NT][4];
#pragma unroll
    for (int t = 0; t < NT; t++)
#pragma unroll
        for (int s = 0; s < 4; s++)
            wf[t][s] = *(const short8*)&Wt[(size_t)(t * 16 + r) * 128 + s * 32 + g * 8];

    const int stride = gridDim.x * 4;
    for (int strip = blockIdx.x * 4 + wid; strip < nstrips; strip += stride) {
        const int R = strip * 16;
        const int ar = min(R + r, M - 1);
        short8 af[4];
#pragma unroll
        for (int s = 0; s < 4; s++)
            af[s] = *(const short8*)&A[(size_t)ar * 128 + s * 32 + g * 8];
        f32x4 acc[NT];
#pragma unroll
        for (int t = 0; t < NT; t++) acc[t] = (f32x4){0.f, 0.f, 0.f, 0.f};
#pragma unroll
        for (int s = 0; s < 4; s++)
#pragma unroll
            for (int t = 0; t < NT; t++)
                acc[t] = __builtin_amdgcn_mfma_f32_16x16x32_bf16(
                    af[s], wf[t][s], acc[t], 0, 0, 0);
#pragma unroll
        for (int j = 0; j < 4; j++) {
            int row = R + 4 * g + j;
            if (row < M) {
#pragma unroll
                for (int t = 0; t < NT; t++)
                    C[(size_t)row * N + t * 16 + r] = f2bf(acc[t][j]);
            }
        }
    }
}

// ---- aggregation, F=128 (bf16 H -> bf16 out): wave/node, 8-deep gathers ---
__global__ __launch_bounds__(256) void agg128_k(const unsigned short* __restrict__ Hb,
                                                const int* __restrict__ rowptr,
                                                const int* __restrict__ col,
                                                const float* __restrict__ dinv,
                                                const float* __restrict__ bias,
                                                unsigned short* __restrict__ outb,
                                                int M, int relu) {
    int node = blockIdx.x * 4 + (threadIdx.x >> 6);
    if (node >= M) return;
    int lane = threadIdx.x & 63;
    const float di = dinv[node];
    const uint32* Hu = (const uint32*)Hb;  // row = 64 uints (128 bf16)
    uint32 su = Hu[(size_t)node * 64 + lane];
    float ax = di * di * bf2f_lo(su);
    float ay = di * di * bf2f_hi(su);
    const int s = rowptr[node], e = rowptr[node + 1];

    for (int base = s; base < e; base += 64) {
        int n = e - base;
        if (n > 64) n = 64;
        int cid = col[base + (lane < n ? lane : 0)];
        float w = di * dinv[cid];
        int j = 0;
        for (; j + 8 <= n; j += 8) {
            int sj[8]; float wj[8]; uint32 u[8];
#pragma unroll
            for (int k = 0; k < 8; k++) {
                sj[k] = __shfl(cid, j + k);
                wj[k] = __shfl(w, j + k);
            }
#pragma unroll
            for (int k = 0; k < 8; k++)
                u[k] = Hu[(size_t)sj[k] * 64 + lane];
#pragma unroll
            for (int k = 0; k < 8; k++) {
                ax = fmaf(wj[k], bf2f_lo(u[k]), ax);
                ay = fmaf(wj[k], bf2f_hi(u[k]), ay);
            }
        }
        for (; j < n; j++) {
            int s0 = __shfl(cid, j);
            float w0 = __shfl(w, j);
            uint32 u0 = Hu[(size_t)s0 * 64 + lane];
            ax = fmaf(w0, bf2f_lo(u0), ax);
            ay = fmaf(w0, bf2f_hi(u0), ay);
        }
    }
    float2 bv = *(const float2*)&bias[lane * 2];
    float ox = ax + bv.x, oy = ay + bv.y;
    if (relu) { ox = fmaxf(ox, 0.f); oy = fmaxf(oy, 0.f); }
    uint32 pk = (uint32)f2bf(ox) | ((uint32)f2bf(oy) << 16);
    *(uint32*)&outb[(size_t)node * 128 + lane * 2] = pk;
}

// ---- aggregation, F=32 (bf16 H -> f32 out): wave/node, halves split -------
__global__ __launch_bounds__(256) void agg32_k(const unsigned short* __restrict__ Hb,
                                               const int* __restrict__ rowptr,
                                               const int* __restrict__ col,
                                               const float* __restrict__ dinv,
                                               const float* __restrict__ bias,
                                               float* __restrict__ out, int M) {
    int node = blockIdx.x * 4 + (threadIdx.x >> 6);
    if (node >= M) return;
    int lane = threadIdx.x & 63;
    int f = lane & 31;
    int half = lane >> 5;
    const float di = dinv[node];
    float acc = 0.f;
    if (!half)
        acc = di * di * __uint_as_float(((uint32)Hb[(size_t)node * 32 + f]) << 16);
    const int s = rowptr[node], e = rowptr[node + 1];
    int i = s + half;
    for (; i + 6 < e; i += 8) {
        int s0 = col[i], s1 = col[i + 2], s2 = col[i + 4], s3 = col[i + 6];
        float w0 = di * dinv[s0], w1 = di * dinv[s1];
        float w2 = di * dinv[s2], w3 = di * dinv[s3];
        float h0 = __uint_as_float(((uint32)Hb[(size_t)s0 * 32 + f]) << 16);
        float h1 = __uint_as_float(((uint32)Hb[(size_t)s1 * 32 + f]) << 16);
        float h2 = __uint_as_float(((uint32)Hb[(size_t)s2 * 32 + f]) << 16);
        float h3 = __uint_as_float(((uint32)Hb[(size_t)s3 * 32 + f]) << 16);
        acc = fmaf(w0, h0, acc);
        acc = fmaf(w1, h1, acc);
        acc = fmaf(w2, h2, acc);
        acc = fmaf(w3, h3, acc);
    }
    for (; i < e; i += 2) {
        int s0 = col[i];
        float h0 = __uint_as_float(((uint32)Hb[(size_t)s0 * 32 + f]) << 16);
        acc = fmaf(di * dinv[s0], h0, acc);
    }
    acc += __shfl_xor(acc, 32);
    if (!half) out[(size_t)node * 32 + f] = acc + bias[f];
}

// ---- global mean pool over sorted batch ids -------------------------------
__global__ __launch_bounds__(256) void pool_k(const float* __restrict__ h,
                                              const int* __restrict__ batch, int M,
                                              float* __restrict__ out) {
    int g = blockIdx.x;
    int lo, hi;
    {
        int l = 0, r = M;
        while (l < r) { int m = (l + r) >> 1; if (batch[m] < g) l = m + 1; else r = m; }
        lo = l;
    }
    {
        int l = lo, r = M;
        while (l < r) { int m = (l + r) >> 1; if (batch[m] < g + 1) l = m + 1; else r = m; }
        hi = l;
    }
    int f = threadIdx.x & 31;
    int chunk = threadIdx.x >> 5;  // 8 chunks
    float acc = 0.f;
    for (int i = lo + chunk; i < hi; i += 8) acc += h[(size_t)i * 32 + f];
    __shared__ float red[8][32];
    red[chunk][f] = acc;
    __syncthreads();
    if (threadIdx.x < 32) {
        float s = 0.f;
#pragma unroll
        for (int c = 0; c < 8; c++) s += red[c][f];
        out[g * 32 + f] = s / fmaxf((float)(hi - lo), 1.f);
    }
}

extern "C" void kernel_launch(void* const* d_in, const int* in_sizes, int n_in,
                              void* d_out, int out_size, void* d_ws, size_t ws_size,
                              hipStream_t stream) {
    const float* x   = (const float*)d_in[0];
    const int* ei    = (const int*)d_in[1];
    const int* batch = (const int*)d_in[2];
    const float* W1  = (const float*)d_in[4];
    const float* b1  = (const float*)d_in[5];
    const float* W2  = (const float*)d_in[6];
    const float* b2  = (const float*)d_in[7];
    const float* W3  = (const float*)d_in[8];
    const float* b3  = (const float*)d_in[9];

    const int M = in_sizes[0] / 128;
    const int E = in_sizes[1] / 2;
    const int G = 64;  // N_GRAPHS (problem constant)
    const int* srcp = ei;
    const int* dstp = ei + E;

    // workspace carve (256B aligned)
    char* p = (char*)d_ws;
    auto carve = [&](size_t bytes) {
        void* r = (void*)p;
        p += (bytes + 255) & ~(size_t)255;
        return r;
    };
    int*   deg    = (int*)carve((size_t)M * 4);
    float* dinv   = (float*)carve((size_t)M * 4);
    int*   rowptr = (int*)carve((size_t)(M + 1) * 4);
    int*   cursor = (int*)carve((size_t)M * 4);
    int*   blksum = (int*)carve(512 * 4);
    int*   col    = (int*)carve((size_t)E * 4);
    unsigned short* Xb = (unsigned short*)carve((size_t)M * 128 * 2);
    unsigned short* Hb = (unsigned short*)carve((size_t)M * 128 * 2);
    unsigned short* Ob = (unsigned short*)carve((size_t)M * 128 * 2);
    unsigned short* Wt1 = (unsigned short*)carve(128 * 128 * 2);
    unsigned short* Wt2 = (unsigned short*)carve(128 * 128 * 2);
    unsigned short* Wt3 = (unsigned short*)carve(32 * 128 * 2);

    float* outh = (float*)d_out;             // [M,32]
    float* outg = outh + (size_t)M * 32;     // [G,32]

    const int nbM = (M + 255) / 256;
    const int nbE = (E + 255) / 256;
    const int nstrips = (M + 15) / 16;
    const int gblk = (nstrips + 7) / 8;      // 4 waves/block, ~2 strips/wave

    cvt_k<<<(M * 128 / 8 + 255) / 256, 256, 0, stream>>>(x, Xb, M * 128 / 8);
    initdeg_k<<<nbM, 256, 0, stream>>>(deg, M);
    count_k<<<nbE, 256, 0, stream>>>(dstp, E, deg);
    mkdinv_k<<<nbM, 256, 0, stream>>>(deg, dinv, M);
    scan1_k<<<nbM, 256, 0, stream>>>(deg, M, blksum);
    scan2_k<<<1, 512, 0, stream>>>(blksum, nbM);
    scan3_k<<<nbM, 256, 0, stream>>>(deg, M, blksum, rowptr, cursor);
    {
        const int nchunk = (E + FILL_CHUNK - 1) / FILL_CHUNK;
        fill_rp_k<<<nchunk * 8, 256, 0, stream>>>(srcp, dstp, E, M, cursor, col);
    }
    wt_k<<<(128 * 128 + 255) / 256, 256, 0, stream>>>(W1, Wt1, 128);
    wt_k<<<(128 * 128 + 255) / 256, 256, 0, stream>>>(W2, Wt2, 128);
    wt_k<<<(32 * 128 + 255) / 256, 256, 0, stream>>>(W3, Wt3, 32);

    // layer 1
    mgemm_k<8><<<gblk, 256, 0, stream>>>(Xb, Wt1, Hb, M, nstrips);
    agg128_k<<<(M + 3) / 4, 256, 0, stream>>>(Hb, rowptr, col, dinv, b1, Ob, M, 1);
    // layer 2
    mgemm_k<8><<<gblk, 256, 0, stream>>>(Ob, Wt2, Hb, M, nstrips);
    agg128_k<<<(M + 3) / 4, 256, 0, stream>>>(Hb, rowptr, col, dinv, b2, Ob, M, 1);
    // layer 3
    mgemm_k<2><<<gblk, 256, 0, stream>>>(Ob, Wt3, Hb, M, nstrips);
    agg32_k<<<(M + 3) / 4, 256, 0, stream>>>(Hb, rowptr, col, dinv, b3, outh, M);
    // pool
    pool_k<<<G, 256, 0, stream>>>(outh, batch, M, outg);
}